// Round 14
// baseline (1243.575 us; speedup 1.0000x reference)
//
#include <hip/hip_runtime.h>
#include <hip/hip_bf16.h>
#include <cstdint>
#include <cstddef>

using bf16 = __hip_bfloat16;

typedef __attribute__((ext_vector_type(8))) short short8;   // bf16x8 MFMA A/B frag
typedef __attribute__((ext_vector_type(4))) float f32x4;    // MFMA C/D frag
typedef __attribute__((ext_vector_type(4))) unsigned short us4;

static constexpr int Bb = 4, Ss = 2048, Hh = 2048, Ii = 8192, Gg = 128;
static constexpr int Mm = Bb * Ss;   // 8192 tokens

#define MEMFENCE() asm volatile("" ::: "memory")
#define BARRIER() do { MEMFENCE(); __builtin_amdgcn_s_barrier(); MEMFENCE(); } while (0)

// ---------------------------------------------------------------------------
// 1-bit group quantization: wq = sign(w) * mean(|w|) per contiguous 128-group.
// ---------------------------------------------------------------------------
__global__ void quant_onebit(const float* __restrict__ w, bf16* __restrict__ wq,
                             int ngroups) {
  int gid = blockIdx.x * 4 + (threadIdx.x >> 6);
  if (gid >= ngroups) return;
  int lane = threadIdx.x & 63;
  size_t base = (size_t)gid * Gg + (size_t)lane * 2;
  float2 v = *(const float2*)(w + base);
  float s = fabsf(v.x) + fabsf(v.y);
#pragma unroll
  for (int m = 32; m >= 1; m >>= 1) s += __shfl_xor(s, m);
  float scale = s * (1.0f / 128.0f);
  float q0 = (v.x > 0.f) ? scale : ((v.x < 0.f) ? -scale : 0.f);
  float q1 = (v.y > 0.f) ? scale : ((v.y < 0.f) ? -scale : 0.f);
  unsigned int p =
      (unsigned int)__builtin_bit_cast(unsigned short, __float2bfloat16(q0)) |
      ((unsigned int)__builtin_bit_cast(unsigned short, __float2bfloat16(q1)) << 16);
  *(unsigned int*)(wq + base) = p;
}

__global__ void cast_f32_bf16(const float* __restrict__ in, bf16* __restrict__ out,
                              size_t n4) {
  size_t i = (size_t)blockIdx.x * blockDim.x + threadIdx.x;
  if (i >= n4) return;
  float4 v = *(const float4*)(in + i * 4);
  us4 o;
  o.x = __builtin_bit_cast(unsigned short, __float2bfloat16(v.x));
  o.y = __builtin_bit_cast(unsigned short, __float2bfloat16(v.y));
  o.z = __builtin_bit_cast(unsigned short, __float2bfloat16(v.z));
  o.w = __builtin_bit_cast(unsigned short, __float2bfloat16(v.w));
  *(us4*)(out + i * 4) = o;
}

// ---------------------------------------------------------------------------
// 256-row GEMM, 16x16x32 MFMA, 32-k slices.
// R14: B operands DIRECT global->register (prefetched 1 slice ahead, T14);
// only A is LDS-staged (4x reuse). LDS traffic/slice 128KB -> 80KB (-37%),
// the larger serial term in the measured LDS<->MFMA serialization.
// A: 4-slice LDS ring (4 x 16KB = 64 KiB), staged 2 slices ahead.
// Per slice s: {vmcnt(2) [retires stageA(s)+loadB(s), keeps stageA(s+1)];
// barrier; loadB(s+1)->regs; read fa; stageA(s+2); 2x[setprio 16 MFMA]}.
// 1 barrier/slice. 64B-row XOR slot-swizzle for A (0 conflicts, 6 rounds).
// B L2 residency: chunk CN=2 (dual, 2MB B-chunk) / CN=1 (single, 4MB).
// DUAL: fused gate/up; B frag quads read 64B contiguous per 4-lane group.
// ---------------------------------------------------------------------------
__device__ __forceinline__ void gload16(const bf16* g, char* l) {
  __builtin_amdgcn_global_load_lds(
      (const __attribute__((address_space(1))) void*)g,
      (__attribute__((address_space(3))) void*)l, 16, 0, 0);
}

// Swizzled frag read: row stride 64 B (4 x 16 B slots), phys slot = s ^ (row>>1)&3.
__device__ __forceinline__ short8 lfrag(const char* part, int row, int s) {
  return *(const short8*)(part + row * 64 + (((s ^ (row >> 1)) & 3) << 4));
}

template <bool DUAL>
__global__ __launch_bounds__(512, 2)
void gemm_bt8(const bf16* __restrict__ A,   // [M,K]
              const bf16* __restrict__ B0,  // [N,K]
              const bf16* __restrict__ B1,  // [N,K] (DUAL)
              bf16* __restrict__ OutBf,     // [M,N] (DUAL)
              float* __restrict__ OutF,     // [M,N] (!DUAL)
              int M, int N, int K) {
  constexpr int BM = 256, BN = DUAL ? 128 : 256;
  constexpr int NF = DUAL ? 2 : 4;        // n-frags per wave (per matrix)
  extern __shared__ char smem[];          // A ring: 4 x 16384 = 65536 B

  const int tid = threadIdx.x;
  const int wid = tid >> 6;               // 0..7
  const int lane = tid & 63;
  const int wr = wid >> 2;                // 0..1 row half
  const int wc = wid & 3;                 // 0..3 col quarter
  const int lrow = lane & 15;
  const int ks = lane >> 4;               // 16B slot 0..3 within 64B k-row

  // ---- locality mapping: XCD-bijective, then chunk N; CN sized so the
  // B-chunk is L2-resident (B now streams through L2 at 4x multiplicity).
  const int nbx = N / BN;
  const int nbm = M / BM;
  const int nwg = (int)gridDim.x;
  const int cpx = nwg >> 3;
  const int wg = (int)blockIdx.x;
  const int L = (wg & 7) * cpx + (wg >> 3);
  constexpr int CN = DUAL ? 2 : 1;
  const int chunk = L / (nbm * CN);
  const int within = L % (nbm * CN);
  const int m0 = (within / CN) * BM;
  const int n0 = (chunk * CN + (within % CN)) * BN;

  const int NS = K / 32;                  // slices: 64 (GEMM1) / 256 (GEMM2)

  // ---- A staging: dest linear (wave base + lane*16); source slot
  // inverse-swizzled so linear write + swizzled read compose to identity.
  const int srow = tid >> 2;                          // 0..127
  const int slog8 = (((tid & 3) ^ ((tid >> 3) & 3)) << 3);
  const bf16* pA0 = A + (size_t)(m0 + srow) * K + slog8;
  const bf16* pA1 = pA0 + (size_t)128 * K;
  const int dA = wid * 1024;

  auto stageA = [&](int s) {              // 2 loads: A rows 0..255, slice s
    char* b = smem + (size_t)(s & 3) * 16384;
    const int koff = s * 32;
    gload16(pA0 + koff, b + dA);
    gload16(pA1 + koff, b + 8192 + dA);
  };

  // ---- B frag pointers (per-lane; 4-lane quads read 64B contiguous)
  const int nfK = 16 * K;                 // row-block stride (elements)
  const bf16* fbp0;
  const bf16* fbp1;
  if constexpr (DUAL) {
    fbp0 = B0 + (size_t)(n0 + wc * 32 + lrow) * K + ks * 8;
    fbp1 = B1 + (size_t)(n0 + wc * 32 + lrow) * K + ks * 8;
  } else {
    fbp0 = B0 + (size_t)(n0 + wc * 64 + lrow) * K + ks * 8;
    fbp1 = fbp0;                          // unused distinction
  }

  const f32x4 vzero = {0.f, 0.f, 0.f, 0.f};
  f32x4 acc0[8][NF];
  f32x4 acc1[DUAL ? 8 : 1][NF];
#pragma unroll
  for (int mf = 0; mf < 8; ++mf)
#pragma unroll
    for (int nf = 0; nf < NF; ++nf) {
      acc0[mf][nf] = vzero;
      if constexpr (DUAL) acc1[mf][nf] = vzero;
    }

  short8 fbX[4], fbY[4], fa[4];

#define LOADB(DST, S)                                                         \
  do {                                                                        \
    const int koff_ = (S) * 32;                                               \
    if constexpr (DUAL) {                                                     \
      DST[0] = *(const short8*)(fbp0 + koff_);                                \
      DST[1] = *(const short8*)(fbp0 + nfK + koff_);                          \
      DST[2] = *(const short8*)(fbp1 + koff_);                                \
      DST[3] = *(const short8*)(fbp1 + nfK + koff_);                          \
    } else {                                                                  \
      DST[0] = *(const short8*)(fbp0 + koff_);                                \
      DST[1] = *(const short8*)(fbp0 + nfK + koff_);                          \
      DST[2] = *(const short8*)(fbp0 + 2 * nfK + koff_);                      \
      DST[3] = *(const short8*)(fbp0 + 3 * nfK + koff_);                      \
    }                                                                         \
  } while (0)

#define SLICE_BODY(S, CUR, NXT)                                               \
  do {                                                                        \
    const int s_ = (S);                                                       \
    if (s_ + 1 < NS) asm volatile("s_waitcnt vmcnt(2)" ::: "memory");         \
    else             asm volatile("s_waitcnt vmcnt(0)" ::: "memory");         \
    BARRIER();                                                                \
    if (s_ + 1 < NS) LOADB(NXT, s_ + 1);                                      \
    const char* Ap_ = smem + (size_t)(s_ & 3) * 16384;                        \
    _Pragma("unroll")                                                         \
    for (int i = 0; i < 4; ++i)                                               \
      fa[i] = lfrag(Ap_, wr * 128 + i * 16 + lrow, ks);                       \
    if (s_ + 2 < NS) stageA(s_ + 2);                                          \
    __builtin_amdgcn_s_setprio(1);                                            \
    _Pragma("unroll")                                                         \
    for (int i = 0; i < 4; ++i)                                               \
      _Pragma("unroll")                                                       \
      for (int nf = 0; nf < NF; ++nf) {                                       \
        acc0[i][nf] = __builtin_amdgcn_mfma_f32_16x16x32_bf16(                \
            fa[i], CUR[nf], acc0[i][nf], 0, 0, 0);                            \
        if constexpr (DUAL)                                                   \
          acc1[i][nf] = __builtin_amdgcn_mfma_f32_16x16x32_bf16(              \
              fa[i], CUR[2 + nf], acc1[i][nf], 0, 0, 0);                      \
      }                                                                       \
    __builtin_amdgcn_s_setprio(0);                                            \
    _Pragma("unroll")                                                         \
    for (int i = 0; i < 4; ++i)                                               \
      fa[i] = lfrag(Ap_, wr * 128 + 64 + i * 16 + lrow, ks);                  \
    __builtin_amdgcn_s_setprio(1);                                            \
    _Pragma("unroll")                                                         \
    for (int i = 0; i < 4; ++i)                                               \
      _Pragma("unroll")                                                       \
      for (int nf = 0; nf < NF; ++nf) {                                       \
        acc0[4 + i][nf] = __builtin_amdgcn_mfma_f32_16x16x32_bf16(            \
            fa[i], CUR[nf], acc0[4 + i][nf], 0, 0, 0);                        \
        if constexpr (DUAL)                                                   \
          acc1[4 + i][nf] = __builtin_amdgcn_mfma_f32_16x16x32_bf16(          \
              fa[i], CUR[2 + nf], acc1[4 + i][nf], 0, 0, 0);                  \
      }                                                                       \
    __builtin_amdgcn_s_setprio(0);                                            \
  } while (0)

  // ---- prologue: loadB(0) then stageA(0), stageA(1)
  // entry-0 queue: [loadB0:4, stageA0:2, stageA1:2] -> vmcnt(2) ledger holds.
  LOADB(fbX, 0);
  stageA(0);
  stageA(1);

  for (int s = 0; s < NS; s += 2) {
    SLICE_BODY(s, fbX, fbY);
    SLICE_BODY(s + 1, fbY, fbX);
  }

#undef SLICE_BODY
#undef LOADB

  // ---- epilogue: C/D layout col=lane&15, row=(lane>>4)*4+j
  const int crow0 = (lane >> 4) * 4;
  const int ccol = lane & 15;
#pragma unroll
  for (int mf = 0; mf < 8; ++mf)
#pragma unroll
    for (int nf = 0; nf < NF; ++nf)
#pragma unroll
      for (int j = 0; j < 4; ++j) {
        const int row = m0 + wr * 128 + mf * 16 + crow0 + j;
        if constexpr (DUAL) {
          const int col = n0 + wc * 32 + nf * 16 + ccol;
          float g = acc0[mf][nf][j];
          float u = acc1[mf][nf][j];
          OutBf[(size_t)row * N + col] =
              __float2bfloat16(g / (1.0f + expf(-g)) * u);
        } else {
          const int col = n0 + wc * 64 + nf * 16 + ccol;
          OutF[(size_t)row * N + col] = acc0[mf][nf][j];
        }
      }
}

// ---------------------------------------------------------------------------
extern "C" void kernel_launch(void* const* d_in, const int* in_sizes, int n_in,
                              void* d_out, int out_size, void* d_ws, size_t ws_size,
                              hipStream_t stream) {
  const float* x = (const float*)d_in[0];
  const float* wg = (const float*)d_in[1];
  const float* wu = (const float*)d_in[2];
  const float* wd = (const float*)d_in[3];
  float* out = (float*)d_out;

  char* ws = (char*)d_ws;
  bf16* xq = (bf16*)(ws + 0);
  bf16* wgq = (bf16*)(ws + (size_t)33554432);
  bf16* wuq = (bf16*)(ws + (size_t)67108864);
  bf16* hbuf = (bf16*)(ws + (size_t)100663296);
  bf16* wdq = xq;  // xq dead after GEMM1

  auto* kDual = gemm_bt8<true>;
  auto* kSingle = gemm_bt8<false>;
  (void)hipFuncSetAttribute((const void*)kDual,
                            hipFuncAttributeMaxDynamicSharedMemorySize, 65536);
  (void)hipFuncSetAttribute((const void*)kSingle,
                            hipFuncAttributeMaxDynamicSharedMemorySize, 65536);

  const int ngW = (Ii * Hh) / Gg;
  quant_onebit<<<ngW / 4, 256, 0, stream>>>(wg, wgq, ngW);
  quant_onebit<<<ngW / 4, 256, 0, stream>>>(wu, wuq, ngW);

  const size_t n4 = (size_t)Mm * Hh / 4;
  cast_f32_bf16<<<(unsigned)((n4 + 255) / 256), 256, 0, stream>>>(x, xq, n4);

  // GEMM1 fused: h = silu(x@wgq^T) * (x@wuq^T)  [M=8192, N=8192, K=2048]
  kDual<<<(Mm / 256) * (Ii / 128), 512, 65536, stream>>>(
      xq, wgq, wuq, hbuf, nullptr, Mm, Ii, Hh);

  quant_onebit<<<ngW / 4, 256, 0, stream>>>(wd, wdq, ngW);

  // GEMM2: out = h @ wdq^T  [M=8192, N=2048, K=8192]
  kSingle<<<(Mm / 256) * (Hh / 256), 512, 65536, stream>>>(
      hbuf, wdq, nullptr, nullptr, out, Mm, Hh, Ii);
}